// Round 11
// baseline (107.044 us; speedup 1.0000x reference)
//
#include <hip/hip_runtime.h>
#include <math.h>

// RankingLoss = mean over rows of sum_{pairs: lab_a-lab_b > TOL} lsig(lg_a-lg_b)
//
// lsig(d) = -ln2*(log2(E_hi + E_lo) - s_hi),  s = logit*log2e, E = 2^s.
// Rows reordered bucket-major by label (bucket width = TOL = 0.01).
// For j < C_i (C_i = start of bucket b_i-1): pair guaranteed valid, i = high.
//   K2 tile core: p *= (E_i + E_j); E_j staged in LDS (b128 broadcast reads);
//   2 VALU/pair, 2 v_log per 16 pairs. The -s_i part sums to -s_i*C_i -> K1.
// Side pairs (C_i <= j < i, bucket distance <= 1): in bucket-major order these
//   have lab_i >= lab_j - (same-bucket disorder < TOL), so valid <=> ld > TOL
//   (exact same f32 predicate as reference) and hi = i always.
//   K1 computes them via diagonal sweep entirely in LDS (no global gathers).
// K1 also: bucket sort (LDS), exports E=2^s and C to global for K2,
//   accumulates -sum(s_i*C_i) and side terms in f64.

#define NN 2048
#define BB 64
#define TOLF 0.01f
#define BLK 256
#define NTILE 36                         // lower-triangular 8x8 tiles
#define TILEBLKS (BB * NTILE)            // 2304
#define LOG2E 1.4426950408889634f

__device__ float  g_Es[BB][NN];
__device__ int    g_C[BB][NN];
__device__ float  g_part[TILEBLKS];
__device__ double g_partA[BB];

// ---------------- K1: bucket reorder + side pairs + corrections (1 blk/row) ----------------
__global__ __launch_bounds__(BLK) void rank_rowprep(const float* __restrict__ logits,
                                                    const float* __restrict__ labels) {
    __shared__ float slab[NN], ss[NN], sEv[NN];
    __shared__ int   sC[NN];
    __shared__ int   cnt[100], pref[101], offs[100];
    __shared__ double dsw[4];
    __shared__ int    isw[4];
    const int row = blockIdx.x, tid = threadIdx.x;
    const float* lg = logits + (size_t)row * NN;
    const float* lb = labels + (size_t)row * NN;

    for (int x = tid; x < 100; x += BLK) { cnt[x] = 0; offs[x] = 0; }
    __syncthreads();
    for (int x = tid; x < NN; x += BLK) {
        int b = min(99, (int)(lb[x] * 100.0f));
        atomicAdd(&cnt[b], 1);
    }
    __syncthreads();
    if (tid == 0) {
        int r = 0;
        for (int b = 0; b < 100; ++b) { pref[b] = r; r += cnt[b]; }
        pref[100] = r;
    }
    __syncthreads();
    for (int x = tid; x < NN; x += BLK) {
        float la = lb[x], lgx = lg[x];
        int b = min(99, (int)(la * 100.0f));
        int p = pref[b] + atomicAdd(&offs[b], 1);
        float s = lgx * LOG2E;
        slab[p] = la; ss[p] = s;
        sEv[p]  = __builtin_amdgcn_exp2f(s);
        sC[p]   = (b >= 1) ? pref[b - 1] : 0;
    }
    __syncthreads();
    // export for tile kernel (coalesced)
    for (int x = tid; x < NN; x += BLK) {
        g_Es[row][x] = sEv[x];
        g_C[row][x]  = sC[x];
    }
    // rowmax = max_i (i - C_i)  (side band width)
    int mymax = 0;
    for (int x = tid; x < NN; x += BLK) mymax = max(mymax, x - sC[x]);
    for (int off = 32; off > 0; off >>= 1) mymax = max(mymax, __shfl_down(mymax, off));
    if ((tid & 63) == 0) isw[tid >> 6] = mymax;
    __syncthreads();
    const int rowmax = max(max(isw[0], isw[1]), max(isw[2], isw[3]));

    // corrections: -sum s_i*C_i  (tile-region s_hi total), exact
    double accD = 0.0;
    for (int x = tid; x < NN; x += BLK)
        accD -= (double)ss[x] * (double)sC[x];

    // side pairs via diagonal sweep, all in LDS
    float accL = 0.0f, accS = 0.0f;
    for (int d = 1; d <= rowmax; ++d) {
        float p = 1.0f;
        for (int x = tid; x < NN; x += BLK) {        // 8 sub-iterations
            int j = x - d;
            bool inwin = (j >= sC[x]);               // j >= 0 implied (sC >= 0)
            int jc = inwin ? j : 0;
            float ld = slab[x] - slab[jc];
            bool valid = inwin && (ld > TOLF);       // exact reference predicate
            float term = valid ? (sEv[x] + sEv[jc]) : 1.0f;
            p *= term;                               // 8 terms <= 2^61: safe
            accS -= valid ? ss[x] : 0.0f;
        }
        accL += __builtin_amdgcn_logf(p);            // v_log_f32 = log2
    }
    accD += (double)accL + (double)accS;

    for (int off = 32; off > 0; off >>= 1) accD += __shfl_down(accD, off);
    if ((tid & 63) == 0) dsw[tid >> 6] = accD;
    __syncthreads();
    if (tid == 0) g_partA[row] = dsw[0] + dsw[1] + dsw[2] + dsw[3];
}

// ---------------- K2: tiles, mask-free core ----------------
__global__ __launch_bounds__(BLK) void rank_tiles() {
    __shared__ __align__(16) float swin[256];        // 1 KB j-window of E
    __shared__ float swave[4];
    const int bid = blockIdx.x;
    const int row = bid / NTILE;                     // block-uniform
    int t = bid % NTILE;
    int it = 0;
    while ((it + 1) * (it + 2) / 2 <= t) ++it;
    const int jt = t - it * (it + 1) / 2;
    const int ibeg = it * 256, jbeg = jt * 256;

    float accL = 0.0f;
    const int Cmax = g_C[row][ibeg + 255];           // C monotone in position
    if (jbeg < Cmax) {
        for (int x = threadIdx.x; x < 64; x += BLK)
            ((float4*)swin)[x] = ((const float4*)&g_Es[row][jbeg])[x];
        __syncthreads();
        const int i = ibeg + threadIdx.x;
        const float Ei = g_Es[row][i];
        int trip = min(g_C[row][i] - jbeg, 256);
        trip = max(trip, 0);
        const int m16 = trip & ~15;

        for (int jj = 0; jj < m16; jj += 16) {
            const float4* q = (const float4*)&swin[jj];   // uniform addr: broadcast
            float4 w0 = q[0], w1 = q[1], w2 = q[2], w3 = q[3];
            float p0 = 1.0f, p1 = 1.0f;
            p0 *= (w0.x + Ei); p0 *= (w0.y + Ei); p0 *= (w0.z + Ei); p0 *= (w0.w + Ei);
            p1 *= (w1.x + Ei); p1 *= (w1.y + Ei); p1 *= (w1.z + Ei); p1 *= (w1.w + Ei);
            p0 *= (w2.x + Ei); p0 *= (w2.y + Ei); p0 *= (w2.z + Ei); p0 *= (w2.w + Ei);
            p1 *= (w3.x + Ei); p1 *= (w3.y + Ei); p1 *= (w3.z + Ei); p1 *= (w3.w + Ei);
            accL += __builtin_amdgcn_logf(p0) + __builtin_amdgcn_logf(p1);
        }
        if (m16 < trip) {                            // <= 15 real terms
            float p0 = 1.0f, p1 = 1.0f;
#pragma unroll
            for (int u = 0; u < 8; ++u) {
                float t0 = (m16 + u     < trip) ? (swin[m16 + u]     + Ei) : 1.0f;
                float t1 = (m16 + 8 + u < trip) ? (swin[m16 + 8 + u] + Ei) : 1.0f;
                p0 *= t0; p1 *= t1;
            }
            accL += __builtin_amdgcn_logf(p0) + __builtin_amdgcn_logf(p1);
        }
    }

    for (int off = 32; off > 0; off >>= 1) accL += __shfl_down(accL, off);
    if ((threadIdx.x & 63) == 0) swave[threadIdx.x >> 6] = accL;
    __syncthreads();
    if (threadIdx.x == 0)
        g_part[bid] = swave[0] + swave[1] + swave[2] + swave[3];
}

// ---------------- K3: final reduce ----------------
__global__ __launch_bounds__(BLK) void rank_final(float* __restrict__ out) {
    double acc = 0.0;
    for (int i = threadIdx.x; i < TILEBLKS; i += BLK) acc += (double)g_part[i];
    for (int i = threadIdx.x; i < BB; i += BLK) acc += g_partA[i];
    for (int off = 32; off > 0; off >>= 1) acc += __shfl_down(acc, off);
    __shared__ double sw[4];
    if ((threadIdx.x & 63) == 0) sw[threadIdx.x >> 6] = acc;
    __syncthreads();
    if (threadIdx.x == 0)
        out[0] = (float)((sw[0] + sw[1] + sw[2] + sw[3]) *
                         (-0.6931471805599453 / (double)BB));
}

extern "C" void kernel_launch(void* const* d_in, const int* in_sizes, int n_in,
                              void* d_out, int out_size, void* d_ws, size_t ws_size,
                              hipStream_t stream) {
    const float* logits = (const float*)d_in[0];
    const float* labels = (const float*)d_in[1];
    float* out = (float*)d_out;
    (void)in_sizes; (void)n_in; (void)out_size; (void)d_ws; (void)ws_size;

    rank_rowprep<<<BB, BLK, 0, stream>>>(logits, labels);
    rank_tiles<<<TILEBLKS, BLK, 0, stream>>>();
    rank_final<<<1, BLK, 0, stream>>>(out);
}

// Round 12
// 91.391 us; speedup vs baseline: 1.1713x; 1.1713x over previous
//
#include <hip/hip_runtime.h>
#include <math.h>

// RankingLoss = mean over rows of sum_{pairs: lab_a-lab_b > TOL} lsig(lg_a-lg_b)
//
// Rows reordered bucket-major by label (bucket width = TOL = 0.01), packed as
// float4 (lab, s=logit*log2e, E=2^s, C-bits). For j < C_i (C_i = start of
// bucket b_i-1) the pair is guaranteed valid with i = high:
//   contribution = -ln2 * log2(1 + E_j/E_i)
//   tile core: t = E_j*invE_i; p = fma(t,p,p); 2 v_log per 16 pairs.
// Side pairs (C_i <= j < i, bucket dist <= 1, ~3%): exact mask |ld|>TOL,
//   orientation by sign(ld), per-pair exp2+log (proven round 7).
// Reduction: per-block partial -> fixed-point int64 atomicAdd (2^20 scale,
//   deterministic) + ticket; last block writes out. No final kernel.

#define NN 2048
#define BB 64
#define TOLF 0.01f
#define BLK 256
#define NTILE 36                         // lower-triangular 8x8 tiles
#define TILEBLKS (BB * NTILE)            // 2304
#define SIDEBLKS (BB * 8)                // 512
#define WGRID (TILEBLKS + SIDEBLKS)      // 2816
#define LOG2E 1.4426950408889634f
#define FIXSCALE 1048576.0               // 2^20

__device__ float4 g_pack[BB][NN];        // (lab, s, E, C-as-int-bits)

// ---------------- K1: bucket-major reorder (1 block/row) ----------------
__global__ __launch_bounds__(BLK) void rank_pre(const float* __restrict__ logits,
                                                const float* __restrict__ labels) {
    __shared__ int cnt[100], offs[100];
    __shared__ int pref[101];
    __shared__ int wtot;
    const int row = blockIdx.x, tid = threadIdx.x;
    const float* lg = logits + (size_t)row * NN;
    const float* lb = labels + (size_t)row * NN;

    for (int x = tid; x < 100; x += BLK) { cnt[x] = 0; offs[x] = 0; }
    __syncthreads();

    int   myb[8];
    float myla[8], mylg[8];
#pragma unroll
    for (int q = 0; q < 8; ++q) {
        int x = tid + q * BLK;
        myla[q] = lb[x];
        mylg[q] = lg[x];
        myb[q]  = min(99, (int)(myla[q] * 100.0f));
        atomicAdd(&cnt[myb[q]], 1);
    }
    __syncthreads();

    // parallel exclusive prefix over 100 counts (waves 0-1 carry the scan)
    {
        int v = (tid < 100) ? cnt[tid] : 0;
        int x = v;
#pragma unroll
        for (int o = 1; o < 64; o <<= 1) {
            int y = __shfl_up(x, o);
            if ((tid & 63) >= o) x += y;
        }
        if (tid == 63) wtot = x;
        __syncthreads();
        if (tid >= 64 && tid < 128) x += wtot;
        if (tid < 101) pref[tid] = x - v;      // exclusive prefix; pref[100]=total
    }
    __syncthreads();

#pragma unroll
    for (int q = 0; q < 8; ++q) {
        int b = myb[q];
        int p = pref[b] + atomicAdd(&offs[b], 1);
        float s = mylg[q] * LOG2E;
        g_pack[row][p] = make_float4(myla[q], s, __builtin_amdgcn_exp2f(s),
                                     __int_as_float((b >= 1) ? pref[b - 1] : 0));
    }
}

// ---------------- K2: tiles + side + merged reduction ----------------
__global__ __launch_bounds__(BLK) void rank_work(float* __restrict__ out,
                                                 unsigned long long* __restrict__ ws) {
    const int bid = blockIdx.x;
    float accL = 0.0f;                       // log2 units, always >= 0

    if (bid < TILEBLKS) {
        __shared__ __align__(16) float swin[256];     // j-window of E
        const int row = bid / NTILE;                  // block-uniform
        int t = bid % NTILE;
        int it = 0;
        while ((it + 1) * (it + 2) / 2 <= t) ++it;
        const int jt = t - it * (it + 1) / 2;
        const int ibeg = it * 256, jbeg = jt * 256;

        const int Cmax = __float_as_int(g_pack[row][ibeg + 255].w);  // C monotone
        if (jbeg < Cmax) {
            swin[threadIdx.x] = g_pack[row][jbeg + threadIdx.x].z;
            __syncthreads();
            const float4 pki = g_pack[row][ibeg + threadIdx.x];
            const float invEi = __builtin_amdgcn_rcpf(pki.z);
            int trip = __float_as_int(pki.w) - jbeg;
            trip = max(0, min(256, trip));
            const int m16 = trip & ~15;

            for (int jj = 0; jj < m16; jj += 16) {
                const float4* q = (const float4*)&swin[jj];   // uniform: broadcast
                float4 w0 = q[0], w1 = q[1], w2 = q[2], w3 = q[3];
                float p0 = 1.0f, p1 = 1.0f;
                p0 = fmaf(w0.x * invEi, p0, p0);
                p0 = fmaf(w0.y * invEi, p0, p0);
                p0 = fmaf(w0.z * invEi, p0, p0);
                p0 = fmaf(w0.w * invEi, p0, p0);
                p1 = fmaf(w1.x * invEi, p1, p1);
                p1 = fmaf(w1.y * invEi, p1, p1);
                p1 = fmaf(w1.z * invEi, p1, p1);
                p1 = fmaf(w1.w * invEi, p1, p1);
                p0 = fmaf(w2.x * invEi, p0, p0);
                p0 = fmaf(w2.y * invEi, p0, p0);
                p0 = fmaf(w2.z * invEi, p0, p0);
                p0 = fmaf(w2.w * invEi, p0, p0);
                p1 = fmaf(w3.x * invEi, p1, p1);
                p1 = fmaf(w3.y * invEi, p1, p1);
                p1 = fmaf(w3.z * invEi, p1, p1);
                p1 = fmaf(w3.w * invEi, p1, p1);
                accL += __builtin_amdgcn_logf(p0) + __builtin_amdgcn_logf(p1);
            }
            if (m16 < trip) {                         // <= 15 real terms, masked
                float p0 = 1.0f, p1 = 1.0f;
#pragma unroll
                for (int u = 0; u < 8; ++u) {
                    float t0 = (m16 + u     < trip) ? swin[m16 + u]     * invEi : 0.0f;
                    float t1 = (m16 + 8 + u < trip) ? swin[m16 + 8 + u] * invEi : 0.0f;
                    p0 = fmaf(t0, p0, p0);
                    p1 = fmaf(t1, p1, p1);
                }
                accL += __builtin_amdgcn_logf(p0) + __builtin_amdgcn_logf(p1);
            }
        }
    } else {
        // side: bucket-distance <= 1 pairs, exact mask + orientation
        const int sb = bid - TILEBLKS;
        const int row = sb >> 3;
        const int i = ((sb & 7) << 8) + threadIdx.x;
        const float4 pki = g_pack[row][i];
        const float lai = pki.x, si = pki.y;
        const int   Ci  = __float_as_int(pki.w);
        for (int jj = Ci; jj < i; ++jj) {
            float4 pkj = g_pack[row][jj];
            float ld = lai - pkj.x;
            float a  = (ld > 0.0f) ? (pkj.y - si) : (si - pkj.y);
            float tq = (fabsf(ld) > TOLF) ? __builtin_amdgcn_exp2f(a) : 0.0f;
            accL += __builtin_amdgcn_logf(1.0f + tq);
        }
    }

    // block reduce + global fixed-point merge
    float v = accL;
    for (int off = 32; off > 0; off >>= 1) v += __shfl_down(v, off);
    __shared__ float swred[4];
    if ((threadIdx.x & 63) == 0) swred[threadIdx.x >> 6] = v;
    __syncthreads();
    if (threadIdx.x == 0) {
        float bs = swred[0] + swred[1] + swred[2] + swred[3];
        long long q = (long long)((double)bs * FIXSCALE + 0.5);
        atomicAdd(ws, (unsigned long long)q);
        __threadfence();
        unsigned int tk = atomicAdd((unsigned int*)(ws + 1), 1u);
        if (tk == WGRID - 1) {
            __threadfence();
            long long tot = (long long)atomicAdd(ws, 0ULL);
            out[0] = (float)((double)tot / FIXSCALE *
                             (-0.6931471805599453 / (double)BB));
        }
    }
}

extern "C" void kernel_launch(void* const* d_in, const int* in_sizes, int n_in,
                              void* d_out, int out_size, void* d_ws, size_t ws_size,
                              hipStream_t stream) {
    const float* logits = (const float*)d_in[0];
    const float* labels = (const float*)d_in[1];
    float* out = (float*)d_out;
    (void)in_sizes; (void)n_in; (void)out_size; (void)ws_size;

    hipMemsetAsync(d_ws, 0, 16, stream);
    rank_pre<<<BB, BLK, 0, stream>>>(logits, labels);
    rank_work<<<WGRID, BLK, 0, stream>>>(out, (unsigned long long*)d_ws);
}

// Round 13
// 32.751 us; speedup vs baseline: 3.2685x; 2.7905x over previous
//
#include <hip/hip_runtime.h>
#include <math.h>

// RankingLoss = mean over rows of sum_{pairs: lab_a-lab_b > TOL} lsig(lg_a-lg_b)
//
// lsig(x) = -ln2*log2(1 + 2^{s_lo - s_hi}),  s = logit*log2e,  E = 2^s.
// Rows reordered bucket-major by label (bucket width = TOL): for j < C_i
// (C_i = start of bucket b_i-1) the pair is guaranteed valid, i = high:
//   per-pair term: t = E_j * invE_i; p = fma(t, p, p); v_log per 8 terms.
// Tiles are 512 i x 256 j: each thread owns i and i+256 so every LDS
// broadcast read of the j-window feeds two pairs (halves LDS-pipe load,
// the round-7 bottleneck). C monotone => trip_a <= trip_b: segments
// [0,m16a) both, [m16a,m16b) b-only, masked remainders (<=15 terms each).
// Side pairs (C_i <= j < i, bucket dist <= 1, ~3%): exact mask |ld|>TOL,
// orientation by sign(ld) (round-7 proven, byte-identical).

#define NN 2048
#define BB 64
#define TOLF 0.01f
#define BLK 256
#define NTILE 20                         // i-tiles of 512: sum(2*it+2, it=0..3)
#define TILEBLKS (BB * NTILE)            // 1280
#define SIDEBLKS (BB * 8)                // 512
#define WGRID (TILEBLKS + SIDEBLKS)      // 1792
#define LOG2E 1.4426950408889634f

__device__ float  g_lab[BB][NN];   // labels, bucket-major order
__device__ float  g_s[BB][NN];     // logit * log2e
__device__ float  g_Es[BB][NN];    // 2^s = e^logit
__device__ int    g_C[BB][NN];     // prefix bound: start of bucket b_i - 1
__device__ float  g_part[TILEBLKS];
__device__ double g_partS[SIDEBLKS];

// ---------------- preprocess: bucket-major reorder, one block per row ----------------
__global__ __launch_bounds__(BLK) void rank_pre(const float* __restrict__ logits,
                                                const float* __restrict__ labels) {
    __shared__ int cnt[100], pref[101], offs[100];
    __shared__ int wtot;
    const int row = blockIdx.x, tid = threadIdx.x;
    const float* lg = logits + (size_t)row * NN;
    const float* lb = labels + (size_t)row * NN;
    for (int x = tid; x < 100; x += BLK) { cnt[x] = 0; offs[x] = 0; }
    __syncthreads();
    for (int x = tid; x < NN; x += BLK) {
        int b = min(99, (int)(lb[x] * 100.0f));
        atomicAdd(&cnt[b], 1);
    }
    __syncthreads();
    // wave-parallel exclusive prefix over 100 counts (waves 0-1)
    {
        int v = (tid < 100) ? cnt[tid] : 0;
        int x = v;
#pragma unroll
        for (int o = 1; o < 64; o <<= 1) {
            int y = __shfl_up(x, o);
            if ((tid & 63) >= o) x += y;
        }
        if (tid == 63) wtot = x;
        __syncthreads();
        if (tid >= 64 && tid < 128) x += wtot;
        if (tid < 101) pref[tid] = x - v;   // exclusive prefix; pref[100] = total
    }
    __syncthreads();
    for (int x = tid; x < NN; x += BLK) {
        float la = lb[x], lgx = lg[x];
        int b = min(99, (int)(la * 100.0f));
        int p = pref[b] + atomicAdd(&offs[b], 1);
        float s = lgx * LOG2E;
        g_lab[row][p] = la;
        g_s[row][p]   = s;
        g_Es[row][p]  = __builtin_amdgcn_exp2f(s);
        g_C[row][p]   = (b >= 1) ? pref[b - 1] : 0;
    }
}

// ---------------- main work: tiles (mask-free core) + side (exact) ----------------
__global__ __launch_bounds__(BLK) void rank_work() {
    const int bid = blockIdx.x;
    if (bid < TILEBLKS) {
        __shared__ __align__(16) float swin[256];   // 1 KB j-window of E
        __shared__ float swave[4];
        const int row = bid / NTILE;                // block-uniform
        const int t = bid % NTILE;
        // i-tile offsets it*(it+1): 0,2,6,12
        const int it = (t < 2) ? 0 : (t < 6) ? 1 : (t < 12) ? 2 : 3;
        const int jt = t - it * (it + 1);
        const int ibeg = it * 512, jbeg = jt * 256;

        float accL = 0.0f;                          // log2 units
        const int Cmax = g_C[row][ibeg + 511];      // C monotone in position
        if (jbeg < Cmax) {
            for (int x = threadIdx.x; x < 64; x += BLK)
                ((float4*)swin)[x] = ((const float4*)&g_Es[row][jbeg])[x];
            __syncthreads();
            const int ia = ibeg + threadIdx.x;
            const int ib = ia + 256;
            const float invEa = __builtin_amdgcn_rcpf(g_Es[row][ia]);
            const float invEb = __builtin_amdgcn_rcpf(g_Es[row][ib]);
            int tripa = max(0, min(256, g_C[row][ia] - jbeg));
            int tripb = max(0, min(256, g_C[row][ib] - jbeg));   // >= tripa
            const int m16a = tripa & ~15;
            const int m16b = tripb & ~15;

            // segment 1: both i's, mask-free
            for (int jj = 0; jj < m16a; jj += 16) {
                const float4* q = (const float4*)&swin[jj];   // uniform: broadcast
                float4 w0 = q[0], w1 = q[1], w2 = q[2], w3 = q[3];
                float pa0 = 1.0f, pa1 = 1.0f, pb0 = 1.0f, pb1 = 1.0f;
                pa0 = fmaf(w0.x * invEa, pa0, pa0); pb0 = fmaf(w0.x * invEb, pb0, pb0);
                pa0 = fmaf(w0.y * invEa, pa0, pa0); pb0 = fmaf(w0.y * invEb, pb0, pb0);
                pa0 = fmaf(w0.z * invEa, pa0, pa0); pb0 = fmaf(w0.z * invEb, pb0, pb0);
                pa0 = fmaf(w0.w * invEa, pa0, pa0); pb0 = fmaf(w0.w * invEb, pb0, pb0);
                pa1 = fmaf(w1.x * invEa, pa1, pa1); pb1 = fmaf(w1.x * invEb, pb1, pb1);
                pa1 = fmaf(w1.y * invEa, pa1, pa1); pb1 = fmaf(w1.y * invEb, pb1, pb1);
                pa1 = fmaf(w1.z * invEa, pa1, pa1); pb1 = fmaf(w1.z * invEb, pb1, pb1);
                pa1 = fmaf(w1.w * invEa, pa1, pa1); pb1 = fmaf(w1.w * invEb, pb1, pb1);
                pa0 = fmaf(w2.x * invEa, pa0, pa0); pb0 = fmaf(w2.x * invEb, pb0, pb0);
                pa0 = fmaf(w2.y * invEa, pa0, pa0); pb0 = fmaf(w2.y * invEb, pb0, pb0);
                pa0 = fmaf(w2.z * invEa, pa0, pa0); pb0 = fmaf(w2.z * invEb, pb0, pb0);
                pa0 = fmaf(w2.w * invEa, pa0, pa0); pb0 = fmaf(w2.w * invEb, pb0, pb0);
                pa1 = fmaf(w3.x * invEa, pa1, pa1); pb1 = fmaf(w3.x * invEb, pb1, pb1);
                pa1 = fmaf(w3.y * invEa, pa1, pa1); pb1 = fmaf(w3.y * invEb, pb1, pb1);
                pa1 = fmaf(w3.z * invEa, pa1, pa1); pb1 = fmaf(w3.z * invEb, pb1, pb1);
                pa1 = fmaf(w3.w * invEa, pa1, pa1); pb1 = fmaf(w3.w * invEb, pb1, pb1);
                accL += __builtin_amdgcn_logf(pa0) + __builtin_amdgcn_logf(pa1)
                      + __builtin_amdgcn_logf(pb0) + __builtin_amdgcn_logf(pb1);
            }
            // segment 2: b only, mask-free
            for (int jj = m16a; jj < m16b; jj += 16) {
                const float4* q = (const float4*)&swin[jj];
                float4 w0 = q[0], w1 = q[1], w2 = q[2], w3 = q[3];
                float pb0 = 1.0f, pb1 = 1.0f;
                pb0 = fmaf(w0.x * invEb, pb0, pb0);
                pb0 = fmaf(w0.y * invEb, pb0, pb0);
                pb0 = fmaf(w0.z * invEb, pb0, pb0);
                pb0 = fmaf(w0.w * invEb, pb0, pb0);
                pb1 = fmaf(w1.x * invEb, pb1, pb1);
                pb1 = fmaf(w1.y * invEb, pb1, pb1);
                pb1 = fmaf(w1.z * invEb, pb1, pb1);
                pb1 = fmaf(w1.w * invEb, pb1, pb1);
                pb0 = fmaf(w2.x * invEb, pb0, pb0);
                pb0 = fmaf(w2.y * invEb, pb0, pb0);
                pb0 = fmaf(w2.z * invEb, pb0, pb0);
                pb0 = fmaf(w2.w * invEb, pb0, pb0);
                pb1 = fmaf(w3.x * invEb, pb1, pb1);
                pb1 = fmaf(w3.y * invEb, pb1, pb1);
                pb1 = fmaf(w3.z * invEb, pb1, pb1);
                pb1 = fmaf(w3.w * invEb, pb1, pb1);
                accL += __builtin_amdgcn_logf(pb0) + __builtin_amdgcn_logf(pb1);
            }
            // masked remainders (<=15 real terms each)
            if (m16a < tripa) {
                float p0 = 1.0f, p1 = 1.0f;
#pragma unroll
                for (int u = 0; u < 8; ++u) {
                    float t0 = (m16a + u     < tripa) ? fmaf(swin[m16a + u],     invEa, 1.0f) : 1.0f;
                    float t1 = (m16a + 8 + u < tripa) ? fmaf(swin[m16a + 8 + u], invEa, 1.0f) : 1.0f;
                    p0 *= t0; p1 *= t1;
                }
                accL += __builtin_amdgcn_logf(p0) + __builtin_amdgcn_logf(p1);
            }
            if (m16b < tripb) {
                float p0 = 1.0f, p1 = 1.0f;
#pragma unroll
                for (int u = 0; u < 8; ++u) {
                    float t0 = (m16b + u     < tripb) ? fmaf(swin[m16b + u],     invEb, 1.0f) : 1.0f;
                    float t1 = (m16b + 8 + u < tripb) ? fmaf(swin[m16b + 8 + u], invEb, 1.0f) : 1.0f;
                    p0 *= t0; p1 *= t1;
                }
                accL += __builtin_amdgcn_logf(p0) + __builtin_amdgcn_logf(p1);
            }
        }
        for (int off = 32; off > 0; off >>= 1) accL += __shfl_down(accL, off);
        if ((threadIdx.x & 63) == 0) swave[threadIdx.x >> 6] = accL;
        __syncthreads();
        if (threadIdx.x == 0)
            g_part[bid] = swave[0] + swave[1] + swave[2] + swave[3];
    } else {
        // side: bucket-distance <= 1 pairs, exact mask + orientation (round-7 proven)
        __shared__ double sdw[4];
        const int sb = bid - TILEBLKS;
        const int row = sb >> 3;
        const int i = ((sb & 7) << 8) + threadIdx.x;
        const float lai = g_lab[row][i];
        const float si  = g_s[row][i];
        const int w0 = g_C[row][i];
        float accL = 0.0f;
        for (int j = w0; j < i; ++j) {
            float ld = lai - g_lab[row][j];
            float sj = g_s[row][j];
            float a  = (ld > 0.0f) ? (sj - si) : (si - sj);
            float tq = (fabsf(ld) > TOLF) ? __builtin_amdgcn_exp2f(a) : 0.0f;
            accL += __builtin_amdgcn_logf(1.0f + tq);
        }
        double acc = (double)accL;
        for (int off = 32; off > 0; off >>= 1) acc += __shfl_down(acc, off);
        if ((threadIdx.x & 63) == 0) sdw[threadIdx.x >> 6] = acc;
        __syncthreads();
        if (threadIdx.x == 0)
            g_partS[sb] = sdw[0] + sdw[1] + sdw[2] + sdw[3];
    }
}

__global__ __launch_bounds__(BLK) void rank_final(float* __restrict__ out) {
    double acc = 0.0;
    for (int idx = threadIdx.x; idx < TILEBLKS; idx += BLK) acc += (double)g_part[idx];
    for (int idx = threadIdx.x; idx < SIDEBLKS; idx += BLK) acc += g_partS[idx];
    for (int off = 32; off > 0; off >>= 1) acc += __shfl_down(acc, off);
    __shared__ double sw[4];
    if ((threadIdx.x & 63) == 0) sw[threadIdx.x >> 6] = acc;
    __syncthreads();
    if (threadIdx.x == 0)
        out[0] = (float)((sw[0] + sw[1] + sw[2] + sw[3]) *
                         (-0.6931471805599453 / (double)BB));
}

extern "C" void kernel_launch(void* const* d_in, const int* in_sizes, int n_in,
                              void* d_out, int out_size, void* d_ws, size_t ws_size,
                              hipStream_t stream) {
    const float* logits = (const float*)d_in[0];
    const float* labels = (const float*)d_in[1];
    float* out = (float*)d_out;
    (void)in_sizes; (void)n_in; (void)out_size; (void)d_ws; (void)ws_size;

    rank_pre<<<BB, BLK, 0, stream>>>(logits, labels);
    rank_work<<<WGRID, BLK, 0, stream>>>();
    rank_final<<<1, BLK, 0, stream>>>(out);
}

// Round 14
// 30.349 us; speedup vs baseline: 3.5271x; 1.0791x over previous
//
#include <hip/hip_runtime.h>
#include <math.h>

// RankingLoss = mean over rows of sum_{pairs: lab_a-lab_b > TOL} lsig(lg_a-lg_b)
//
// lsig(x) = -ln2*log2(1 + 2^{s_lo - s_hi}),  s = logit*log2e,  E = 2^s.
// Rows reordered bucket-major by label (bucket width = TOL): for j < C_i
// (C_i = start of bucket b_i-1) the pair is guaranteed valid, i = high:
//   per-pair term: t = E_j * invE_i; p = fma(t, p, p); v_log per 8 terms.
// Tiles are 512 i x 256 j (two i's per thread share each LDS broadcast).
// Side pairs (C_i <= j < i, bucket dist <= 1): exact mask + orientation.
// ROUND-14 CHANGE (single variable): rank_pre scatters into LDS, then
// exports coalesced — kills the scattered-global-store overhead (~10 us
// at 64 blocks with no TLP). rank_work / rank_final identical to round 13.

#define NN 2048
#define BB 64
#define TOLF 0.01f
#define BLK 256
#define NTILE 20                         // i-tiles of 512: sum(2*it+2, it=0..3)
#define TILEBLKS (BB * NTILE)            // 1280
#define SIDEBLKS (BB * 8)                // 512
#define WGRID (TILEBLKS + SIDEBLKS)      // 1792
#define LOG2E 1.4426950408889634f

__device__ float  g_lab[BB][NN];   // labels, bucket-major order
__device__ float  g_s[BB][NN];     // logit * log2e
__device__ float  g_Es[BB][NN];    // 2^s = e^logit
__device__ int    g_C[BB][NN];     // prefix bound: start of bucket b_i - 1
__device__ float  g_part[TILEBLKS];
__device__ double g_partS[SIDEBLKS];

// ---------------- preprocess: bucket reorder via LDS, coalesced export ----------------
__global__ __launch_bounds__(BLK) void rank_pre(const float* __restrict__ logits,
                                                const float* __restrict__ labels) {
    __shared__ float slab[NN], ss[NN], sEv[NN];
    __shared__ int   sC[NN];
    __shared__ int   cnt[100], pref[101], offs[100];
    __shared__ int   wtot;
    const int row = blockIdx.x, tid = threadIdx.x;
    const float* lg = logits + (size_t)row * NN;
    const float* lb = labels + (size_t)row * NN;

    for (int x = tid; x < 100; x += BLK) { cnt[x] = 0; offs[x] = 0; }
    __syncthreads();

    int   myb[8];
    float myla[8], mylg[8];
#pragma unroll
    for (int q = 0; q < 8; ++q) {
        int x = tid + q * BLK;
        myla[q] = lb[x];
        mylg[q] = lg[x];
        myb[q]  = min(99, (int)(myla[q] * 100.0f));
        atomicAdd(&cnt[myb[q]], 1);
    }
    __syncthreads();

    // wave-parallel exclusive prefix over 100 counts (waves 0-1)
    {
        int v = (tid < 100) ? cnt[tid] : 0;
        int x = v;
#pragma unroll
        for (int o = 1; o < 64; o <<= 1) {
            int y = __shfl_up(x, o);
            if ((tid & 63) >= o) x += y;
        }
        if (tid == 63) wtot = x;
        __syncthreads();
        if (tid >= 64 && tid < 128) x += wtot;
        if (tid < 101) pref[tid] = x - v;   // exclusive prefix
    }
    __syncthreads();

    // scatter into LDS (cheap), not global
#pragma unroll
    for (int q = 0; q < 8; ++q) {
        int b = myb[q];
        int p = pref[b] + atomicAdd(&offs[b], 1);
        float s = mylg[q] * LOG2E;
        slab[p] = myla[q];
        ss[p]   = s;
        sEv[p]  = __builtin_amdgcn_exp2f(s);
        sC[p]   = (b >= 1) ? pref[b - 1] : 0;
    }
    __syncthreads();

    // coalesced export
    for (int x = tid; x < NN; x += BLK) {
        g_lab[row][x] = slab[x];
        g_s[row][x]   = ss[x];
        g_Es[row][x]  = sEv[x];
        g_C[row][x]   = sC[x];
    }
}

// ---------------- main work: tiles (mask-free core) + side (exact) ----------------
__global__ __launch_bounds__(BLK) void rank_work() {
    const int bid = blockIdx.x;
    if (bid < TILEBLKS) {
        __shared__ __align__(16) float swin[256];   // 1 KB j-window of E
        __shared__ float swave[4];
        const int row = bid / NTILE;                // block-uniform
        const int t = bid % NTILE;
        // i-tile offsets it*(it+1): 0,2,6,12
        const int it = (t < 2) ? 0 : (t < 6) ? 1 : (t < 12) ? 2 : 3;
        const int jt = t - it * (it + 1);
        const int ibeg = it * 512, jbeg = jt * 256;

        float accL = 0.0f;                          // log2 units
        const int Cmax = g_C[row][ibeg + 511];      // C monotone in position
        if (jbeg < Cmax) {
            for (int x = threadIdx.x; x < 64; x += BLK)
                ((float4*)swin)[x] = ((const float4*)&g_Es[row][jbeg])[x];
            __syncthreads();
            const int ia = ibeg + threadIdx.x;
            const int ib = ia + 256;
            const float invEa = __builtin_amdgcn_rcpf(g_Es[row][ia]);
            const float invEb = __builtin_amdgcn_rcpf(g_Es[row][ib]);
            int tripa = max(0, min(256, g_C[row][ia] - jbeg));
            int tripb = max(0, min(256, g_C[row][ib] - jbeg));   // >= tripa
            const int m16a = tripa & ~15;
            const int m16b = tripb & ~15;

            // segment 1: both i's, mask-free
            for (int jj = 0; jj < m16a; jj += 16) {
                const float4* q = (const float4*)&swin[jj];   // uniform: broadcast
                float4 w0 = q[0], w1 = q[1], w2 = q[2], w3 = q[3];
                float pa0 = 1.0f, pa1 = 1.0f, pb0 = 1.0f, pb1 = 1.0f;
                pa0 = fmaf(w0.x * invEa, pa0, pa0); pb0 = fmaf(w0.x * invEb, pb0, pb0);
                pa0 = fmaf(w0.y * invEa, pa0, pa0); pb0 = fmaf(w0.y * invEb, pb0, pb0);
                pa0 = fmaf(w0.z * invEa, pa0, pa0); pb0 = fmaf(w0.z * invEb, pb0, pb0);
                pa0 = fmaf(w0.w * invEa, pa0, pa0); pb0 = fmaf(w0.w * invEb, pb0, pb0);
                pa1 = fmaf(w1.x * invEa, pa1, pa1); pb1 = fmaf(w1.x * invEb, pb1, pb1);
                pa1 = fmaf(w1.y * invEa, pa1, pa1); pb1 = fmaf(w1.y * invEb, pb1, pb1);
                pa1 = fmaf(w1.z * invEa, pa1, pa1); pb1 = fmaf(w1.z * invEb, pb1, pb1);
                pa1 = fmaf(w1.w * invEa, pa1, pa1); pb1 = fmaf(w1.w * invEb, pb1, pb1);
                pa0 = fmaf(w2.x * invEa, pa0, pa0); pb0 = fmaf(w2.x * invEb, pb0, pb0);
                pa0 = fmaf(w2.y * invEa, pa0, pa0); pb0 = fmaf(w2.y * invEb, pb0, pb0);
                pa0 = fmaf(w2.z * invEa, pa0, pa0); pb0 = fmaf(w2.z * invEb, pb0, pb0);
                pa0 = fmaf(w2.w * invEa, pa0, pa0); pb0 = fmaf(w2.w * invEb, pb0, pb0);
                pa1 = fmaf(w3.x * invEa, pa1, pa1); pb1 = fmaf(w3.x * invEb, pb1, pb1);
                pa1 = fmaf(w3.y * invEa, pa1, pa1); pb1 = fmaf(w3.y * invEb, pb1, pb1);
                pa1 = fmaf(w3.z * invEa, pa1, pa1); pb1 = fmaf(w3.z * invEb, pb1, pb1);
                pa1 = fmaf(w3.w * invEa, pa1, pa1); pb1 = fmaf(w3.w * invEb, pb1, pb1);
                accL += __builtin_amdgcn_logf(pa0) + __builtin_amdgcn_logf(pa1)
                      + __builtin_amdgcn_logf(pb0) + __builtin_amdgcn_logf(pb1);
            }
            // segment 2: b only, mask-free
            for (int jj = m16a; jj < m16b; jj += 16) {
                const float4* q = (const float4*)&swin[jj];
                float4 w0 = q[0], w1 = q[1], w2 = q[2], w3 = q[3];
                float pb0 = 1.0f, pb1 = 1.0f;
                pb0 = fmaf(w0.x * invEb, pb0, pb0);
                pb0 = fmaf(w0.y * invEb, pb0, pb0);
                pb0 = fmaf(w0.z * invEb, pb0, pb0);
                pb0 = fmaf(w0.w * invEb, pb0, pb0);
                pb1 = fmaf(w1.x * invEb, pb1, pb1);
                pb1 = fmaf(w1.y * invEb, pb1, pb1);
                pb1 = fmaf(w1.z * invEb, pb1, pb1);
                pb1 = fmaf(w1.w * invEb, pb1, pb1);
                pb0 = fmaf(w2.x * invEb, pb0, pb0);
                pb0 = fmaf(w2.y * invEb, pb0, pb0);
                pb0 = fmaf(w2.z * invEb, pb0, pb0);
                pb0 = fmaf(w2.w * invEb, pb0, pb0);
                pb1 = fmaf(w3.x * invEb, pb1, pb1);
                pb1 = fmaf(w3.y * invEb, pb1, pb1);
                pb1 = fmaf(w3.z * invEb, pb1, pb1);
                pb1 = fmaf(w3.w * invEb, pb1, pb1);
                accL += __builtin_amdgcn_logf(pb0) + __builtin_amdgcn_logf(pb1);
            }
            // masked remainders (<=15 real terms each)
            if (m16a < tripa) {
                float p0 = 1.0f, p1 = 1.0f;
#pragma unroll
                for (int u = 0; u < 8; ++u) {
                    float t0 = (m16a + u     < tripa) ? fmaf(swin[m16a + u],     invEa, 1.0f) : 1.0f;
                    float t1 = (m16a + 8 + u < tripa) ? fmaf(swin[m16a + 8 + u], invEa, 1.0f) : 1.0f;
                    p0 *= t0; p1 *= t1;
                }
                accL += __builtin_amdgcn_logf(p0) + __builtin_amdgcn_logf(p1);
            }
            if (m16b < tripb) {
                float p0 = 1.0f, p1 = 1.0f;
#pragma unroll
                for (int u = 0; u < 8; ++u) {
                    float t0 = (m16b + u     < tripb) ? fmaf(swin[m16b + u],     invEb, 1.0f) : 1.0f;
                    float t1 = (m16b + 8 + u < tripb) ? fmaf(swin[m16b + 8 + u], invEb, 1.0f) : 1.0f;
                    p0 *= t0; p1 *= t1;
                }
                accL += __builtin_amdgcn_logf(p0) + __builtin_amdgcn_logf(p1);
            }
        }
        for (int off = 32; off > 0; off >>= 1) accL += __shfl_down(accL, off);
        if ((threadIdx.x & 63) == 0) swave[threadIdx.x >> 6] = accL;
        __syncthreads();
        if (threadIdx.x == 0)
            g_part[bid] = swave[0] + swave[1] + swave[2] + swave[3];
    } else {
        // side: bucket-distance <= 1 pairs, exact mask + orientation (round-7 proven)
        __shared__ double sdw[4];
        const int sb = bid - TILEBLKS;
        const int row = sb >> 3;
        const int i = ((sb & 7) << 8) + threadIdx.x;
        const float lai = g_lab[row][i];
        const float si  = g_s[row][i];
        const int w0 = g_C[row][i];
        float accL = 0.0f;
        for (int j = w0; j < i; ++j) {
            float ld = lai - g_lab[row][j];
            float sj = g_s[row][j];
            float a  = (ld > 0.0f) ? (sj - si) : (si - sj);
            float tq = (fabsf(ld) > TOLF) ? __builtin_amdgcn_exp2f(a) : 0.0f;
            accL += __builtin_amdgcn_logf(1.0f + tq);
        }
        double acc = (double)accL;
        for (int off = 32; off > 0; off >>= 1) acc += __shfl_down(acc, off);
        if ((threadIdx.x & 63) == 0) sdw[threadIdx.x >> 6] = acc;
        __syncthreads();
        if (threadIdx.x == 0)
            g_partS[sb] = sdw[0] + sdw[1] + sdw[2] + sdw[3];
    }
}

__global__ __launch_bounds__(BLK) void rank_final(float* __restrict__ out) {
    double acc = 0.0;
    for (int idx = threadIdx.x; idx < TILEBLKS; idx += BLK) acc += (double)g_part[idx];
    for (int idx = threadIdx.x; idx < SIDEBLKS; idx += BLK) acc += g_partS[idx];
    for (int off = 32; off > 0; off >>= 1) acc += __shfl_down(acc, off);
    __shared__ double sw[4];
    if ((threadIdx.x & 63) == 0) sw[threadIdx.x >> 6] = acc;
    __syncthreads();
    if (threadIdx.x == 0)
        out[0] = (float)((sw[0] + sw[1] + sw[2] + sw[3]) *
                         (-0.6931471805599453 / (double)BB));
}

extern "C" void kernel_launch(void* const* d_in, const int* in_sizes, int n_in,
                              void* d_out, int out_size, void* d_ws, size_t ws_size,
                              hipStream_t stream) {
    const float* logits = (const float*)d_in[0];
    const float* labels = (const float*)d_in[1];
    float* out = (float*)d_out;
    (void)in_sizes; (void)n_in; (void)out_size; (void)d_ws; (void)ws_size;

    rank_pre<<<BB, BLK, 0, stream>>>(logits, labels);
    rank_work<<<WGRID, BLK, 0, stream>>>();
    rank_final<<<1, BLK, 0, stream>>>(out);
}

// Round 15
// 27.126 us; speedup vs baseline: 3.9462x; 1.1188x over previous
//
#include <hip/hip_runtime.h>
#include <math.h>

// RankingLoss = mean over rows of sum_{pairs: lab_a-lab_b > TOL} lsig(lg_a-lg_b)
//
// lsig(x) = -ln2*log2(1 + 2^{s_lo - s_hi}),  s = logit*log2e,  E = 2^s.
// Rows reordered bucket-major by label (bucket width = TOL). For j < C_i
// (C_i = start of bucket b_i-1) pair guaranteed valid, i = high:
//   tile core: t = E_j*invE_i; p = fma(t,p,p); v_log per 8; 512i x 256j tiles.
// Side pairs (C_i <= j < i, bucket dist <= 1): |ld|>TOL mask, orientation by
//   sign(ld); term=(Ei+Ej) product + accS -= s_hi (trans-free, r9/r11-proven);
//   window staged in LDS (kills gather latency); side blocks FIRST in grid
//   (kills the tail).
// rank_pre: bucket reorder via LDS, coalesced export (r14-proven).

#define NN 2048
#define BB 64
#define TOLF 0.01f
#define BLK 256
#define NTILE 20                         // i-tiles of 512: offsets it*(it+1)
#define TILEBLKS (BB * NTILE)            // 1280
#define SIDEBLKS (BB * 8)                // 512
#define WGRID (TILEBLKS + SIDEBLKS)      // 1792
#define SWIN 448                         // side LDS window capacity
#define LOG2E 1.4426950408889634f

__device__ float2 g_labs[BB][NN];  // (label, s) bucket-major
__device__ float  g_Es[BB][NN];    // 2^s = e^logit
__device__ int    g_C[BB][NN];     // start of bucket b_i - 1
__device__ float  g_part[TILEBLKS];
__device__ double g_partS[SIDEBLKS];

// ---------------- preprocess: bucket reorder via LDS, coalesced export ----------------
__global__ __launch_bounds__(BLK) void rank_pre(const float* __restrict__ logits,
                                                const float* __restrict__ labels) {
    __shared__ float2 sls[NN];
    __shared__ float  sEv[NN];
    __shared__ int    sC[NN];
    __shared__ int    cnt[100], pref[101], offs[100];
    __shared__ int    wtot;
    const int row = blockIdx.x, tid = threadIdx.x;
    const float* lg = logits + (size_t)row * NN;
    const float* lb = labels + (size_t)row * NN;

    for (int x = tid; x < 100; x += BLK) { cnt[x] = 0; offs[x] = 0; }
    __syncthreads();

    int   myb[8];
    float myla[8], mylg[8];
#pragma unroll
    for (int q = 0; q < 8; ++q) {
        int x = tid + q * BLK;
        myla[q] = lb[x];
        mylg[q] = lg[x];
        myb[q]  = min(99, (int)(myla[q] * 100.0f));
        atomicAdd(&cnt[myb[q]], 1);
    }
    __syncthreads();
    {   // wave-parallel exclusive prefix over 100 counts
        int v = (tid < 100) ? cnt[tid] : 0;
        int x = v;
#pragma unroll
        for (int o = 1; o < 64; o <<= 1) {
            int y = __shfl_up(x, o);
            if ((tid & 63) >= o) x += y;
        }
        if (tid == 63) wtot = x;
        __syncthreads();
        if (tid >= 64 && tid < 128) x += wtot;
        if (tid < 101) pref[tid] = x - v;
    }
    __syncthreads();
#pragma unroll
    for (int q = 0; q < 8; ++q) {
        int b = myb[q];
        int p = pref[b] + atomicAdd(&offs[b], 1);
        float s = mylg[q] * LOG2E;
        sls[p] = make_float2(myla[q], s);
        sEv[p] = __builtin_amdgcn_exp2f(s);
        sC[p]  = (b >= 1) ? pref[b - 1] : 0;
    }
    __syncthreads();
    for (int x = tid; x < NN; x += BLK) {
        g_labs[row][x] = sls[x];
        g_Es[row][x]   = sEv[x];
        g_C[row][x]    = sC[x];
    }
}

// ---------------- main work: side (LDS-staged, first) + tiles ----------------
__global__ __launch_bounds__(BLK) void rank_work() {
    const int bid = blockIdx.x;
    if (bid < SIDEBLKS) {
        // ---- side: bucket-distance <= 1 pairs, windows staged in LDS ----
        __shared__ float2 sLS[SWIN];
        __shared__ float  sE[SWIN];
        __shared__ int    sCs;
        __shared__ double sdw[4];
        const int row = bid >> 3;
        const int c0  = (bid & 7) << 8;
        const int tid = threadIdx.x;
        if (tid == 0) sCs = g_C[row][c0];
        __syncthreads();
        const int Cs  = sCs;
        const int len = c0 + 256 - Cs;             // <= ~350 for this data
        for (int x = tid; x < len; x += BLK) {
            sLS[x] = g_labs[row][Cs + x];
            sE[x]  = g_Es[row][Cs + x];
        }
        __syncthreads();

        const int i    = c0 + tid;
        const int iloc = i - Cs;
        const float2 lsi = sLS[iloc];
        const float lai = lsi.x, si = lsi.y;
        const float Ei  = sE[iloc];
        const int wloc  = g_C[row][i] - Cs;

        float accL = 0.0f, accS = 0.0f;
        float p = 1.0f;
        int cnt8 = 0;
        for (int j = wloc; j < iloc; ++j) {
            float2 ls = sLS[j];
            float ld = lai - ls.x;
            bool valid = fabsf(ld) > TOLF;         // exact reference predicate
            float term = valid ? (Ei + sE[j]) : 1.0f;
            p *= term;
            if (++cnt8 == 8) { accL += __builtin_amdgcn_logf(p); p = 1.0f; cnt8 = 0; }
            float sh = (ld > 0.0f) ? si : ls.y;
            accS -= valid ? sh : 0.0f;
        }
        accL += __builtin_amdgcn_logf(p);

        double acc = (double)accL + (double)accS;
        for (int off = 32; off > 0; off >>= 1) acc += __shfl_down(acc, off);
        if ((tid & 63) == 0) sdw[tid >> 6] = acc;
        __syncthreads();
        if (tid == 0) g_partS[bid] = sdw[0] + sdw[1] + sdw[2] + sdw[3];
    } else {
        // ---- tiles: mask-free core (r13/r14-proven) ----
        __shared__ __align__(16) float swin[256];
        __shared__ float swave[4];
        const int tb = bid - SIDEBLKS;
        const int row = tb / NTILE;                // block-uniform
        const int t = tb % NTILE;
        const int it = (t < 2) ? 0 : (t < 6) ? 1 : (t < 12) ? 2 : 3;
        const int jt = t - it * (it + 1);
        const int ibeg = it * 512, jbeg = jt * 256;

        float accL = 0.0f;
        const int Cmax = g_C[row][ibeg + 511];     // C monotone in position
        if (jbeg < Cmax) {
            for (int x = threadIdx.x; x < 64; x += BLK)
                ((float4*)swin)[x] = ((const float4*)&g_Es[row][jbeg])[x];
            __syncthreads();
            const int ia = ibeg + threadIdx.x;
            const int ib = ia + 256;
            const float invEa = __builtin_amdgcn_rcpf(g_Es[row][ia]);
            const float invEb = __builtin_amdgcn_rcpf(g_Es[row][ib]);
            int tripa = max(0, min(256, g_C[row][ia] - jbeg));
            int tripb = max(0, min(256, g_C[row][ib] - jbeg));   // >= tripa
            const int m16a = tripa & ~15;
            const int m16b = tripb & ~15;

            for (int jj = 0; jj < m16a; jj += 16) {
                const float4* q = (const float4*)&swin[jj];   // uniform: broadcast
                float4 w0 = q[0], w1 = q[1], w2 = q[2], w3 = q[3];
                float pa0 = 1.0f, pa1 = 1.0f, pb0 = 1.0f, pb1 = 1.0f;
                pa0 = fmaf(w0.x * invEa, pa0, pa0); pb0 = fmaf(w0.x * invEb, pb0, pb0);
                pa0 = fmaf(w0.y * invEa, pa0, pa0); pb0 = fmaf(w0.y * invEb, pb0, pb0);
                pa0 = fmaf(w0.z * invEa, pa0, pa0); pb0 = fmaf(w0.z * invEb, pb0, pb0);
                pa0 = fmaf(w0.w * invEa, pa0, pa0); pb0 = fmaf(w0.w * invEb, pb0, pb0);
                pa1 = fmaf(w1.x * invEa, pa1, pa1); pb1 = fmaf(w1.x * invEb, pb1, pb1);
                pa1 = fmaf(w1.y * invEa, pa1, pa1); pb1 = fmaf(w1.y * invEb, pb1, pb1);
                pa1 = fmaf(w1.z * invEa, pa1, pa1); pb1 = fmaf(w1.z * invEb, pb1, pb1);
                pa1 = fmaf(w1.w * invEa, pa1, pa1); pb1 = fmaf(w1.w * invEb, pb1, pb1);
                pa0 = fmaf(w2.x * invEa, pa0, pa0); pb0 = fmaf(w2.x * invEb, pb0, pb0);
                pa0 = fmaf(w2.y * invEa, pa0, pa0); pb0 = fmaf(w2.y * invEb, pb0, pb0);
                pa0 = fmaf(w2.z * invEa, pa0, pa0); pb0 = fmaf(w2.z * invEb, pb0, pb0);
                pa0 = fmaf(w2.w * invEa, pa0, pa0); pb0 = fmaf(w2.w * invEb, pb0, pb0);
                pa1 = fmaf(w3.x * invEa, pa1, pa1); pb1 = fmaf(w3.x * invEb, pb1, pb1);
                pa1 = fmaf(w3.y * invEa, pa1, pa1); pb1 = fmaf(w3.y * invEb, pb1, pb1);
                pa1 = fmaf(w3.z * invEa, pa1, pa1); pb1 = fmaf(w3.z * invEb, pb1, pb1);
                pa1 = fmaf(w3.w * invEa, pa1, pa1); pb1 = fmaf(w3.w * invEb, pb1, pb1);
                accL += __builtin_amdgcn_logf(pa0) + __builtin_amdgcn_logf(pa1)
                      + __builtin_amdgcn_logf(pb0) + __builtin_amdgcn_logf(pb1);
            }
            for (int jj = m16a; jj < m16b; jj += 16) {
                const float4* q = (const float4*)&swin[jj];
                float4 w0 = q[0], w1 = q[1], w2 = q[2], w3 = q[3];
                float pb0 = 1.0f, pb1 = 1.0f;
                pb0 = fmaf(w0.x * invEb, pb0, pb0);
                pb0 = fmaf(w0.y * invEb, pb0, pb0);
                pb0 = fmaf(w0.z * invEb, pb0, pb0);
                pb0 = fmaf(w0.w * invEb, pb0, pb0);
                pb1 = fmaf(w1.x * invEb, pb1, pb1);
                pb1 = fmaf(w1.y * invEb, pb1, pb1);
                pb1 = fmaf(w1.z * invEb, pb1, pb1);
                pb1 = fmaf(w1.w * invEb, pb1, pb1);
                pb0 = fmaf(w2.x * invEb, pb0, pb0);
                pb0 = fmaf(w2.y * invEb, pb0, pb0);
                pb0 = fmaf(w2.z * invEb, pb0, pb0);
                pb0 = fmaf(w2.w * invEb, pb0, pb0);
                pb1 = fmaf(w3.x * invEb, pb1, pb1);
                pb1 = fmaf(w3.y * invEb, pb1, pb1);
                pb1 = fmaf(w3.z * invEb, pb1, pb1);
                pb1 = fmaf(w3.w * invEb, pb1, pb1);
                accL += __builtin_amdgcn_logf(pb0) + __builtin_amdgcn_logf(pb1);
            }
            if (m16a < tripa) {
                float p0 = 1.0f, p1 = 1.0f;
#pragma unroll
                for (int u = 0; u < 8; ++u) {
                    float t0 = (m16a + u     < tripa) ? fmaf(swin[m16a + u],     invEa, 1.0f) : 1.0f;
                    float t1 = (m16a + 8 + u < tripa) ? fmaf(swin[m16a + 8 + u], invEa, 1.0f) : 1.0f;
                    p0 *= t0; p1 *= t1;
                }
                accL += __builtin_amdgcn_logf(p0) + __builtin_amdgcn_logf(p1);
            }
            if (m16b < tripb) {
                float p0 = 1.0f, p1 = 1.0f;
#pragma unroll
                for (int u = 0; u < 8; ++u) {
                    float t0 = (m16b + u     < tripb) ? fmaf(swin[m16b + u],     invEb, 1.0f) : 1.0f;
                    float t1 = (m16b + 8 + u < tripb) ? fmaf(swin[m16b + 8 + u], invEb, 1.0f) : 1.0f;
                    p0 *= t0; p1 *= t1;
                }
                accL += __builtin_amdgcn_logf(p0) + __builtin_amdgcn_logf(p1);
            }
        }
        for (int off = 32; off > 0; off >>= 1) accL += __shfl_down(accL, off);
        if ((threadIdx.x & 63) == 0) swave[threadIdx.x >> 6] = accL;
        __syncthreads();
        if (threadIdx.x == 0)
            g_part[tb] = swave[0] + swave[1] + swave[2] + swave[3];
    }
}

__global__ __launch_bounds__(BLK) void rank_final(float* __restrict__ out) {
    double acc = 0.0;
    for (int idx = threadIdx.x; idx < TILEBLKS; idx += BLK) acc += (double)g_part[idx];
    for (int idx = threadIdx.x; idx < SIDEBLKS; idx += BLK) acc += g_partS[idx];
    for (int off = 32; off > 0; off >>= 1) acc += __shfl_down(acc, off);
    __shared__ double sw[4];
    if ((threadIdx.x & 63) == 0) sw[threadIdx.x >> 6] = acc;
    __syncthreads();
    if (threadIdx.x == 0)
        out[0] = (float)((sw[0] + sw[1] + sw[2] + sw[3]) *
                         (-0.6931471805599453 / (double)BB));
}

extern "C" void kernel_launch(void* const* d_in, const int* in_sizes, int n_in,
                              void* d_out, int out_size, void* d_ws, size_t ws_size,
                              hipStream_t stream) {
    const float* logits = (const float*)d_in[0];
    const float* labels = (const float*)d_in[1];
    float* out = (float*)d_out;
    (void)in_sizes; (void)n_in; (void)out_size; (void)d_ws; (void)ws_size;

    rank_pre<<<BB, BLK, 0, stream>>>(logits, labels);
    rank_work<<<WGRID, BLK, 0, stream>>>();
    rank_final<<<1, BLK, 0, stream>>>(out);
}